// Round 1
// baseline (928.869 us; speedup 1.0000x reference)
//
#include <hip/hip_runtime.h>
#include <math.h>

#define H 4096
#define NLAYERS 8

// One wave (64 lanes) per output row. Block = 256 threads = 4 rows.
// Grid = H/4 = 1024 blocks (~4 blocks/CU on 256 CUs, 16 waves/CU).
// x (16 KiB) staged in LDS once per block; W row read as float4 (16 B/lane,
// 16 fully-unrolled iterations -> 16 loads in flight per wave).
__global__ __launch_bounds__(256) void gemv_bias_act(
    const float* __restrict__ W,   // [H, H] row-major (row r dotted with x)
    const float* __restrict__ b1,  // [H]
    const float* __restrict__ b2,  // [H] or nullptr
    const float* __restrict__ x,   // [H]
    float* __restrict__ y,         // [H]
    int do_tanh)
{
    __shared__ float sx[H];

    // Cooperative staging of x into LDS, 16 B per thread per iter.
    const float4* __restrict__ x4 = (const float4*)x;
    float4* sx4 = (float4*)sx;
#pragma unroll
    for (int i = 0; i < H / 4 / 256; ++i) {          // 4 iters
        sx4[threadIdx.x + i * 256] = x4[threadIdx.x + i * 256];
    }
    __syncthreads();

    const int lane = threadIdx.x & 63;
    const int wave = threadIdx.x >> 6;
    const int row  = blockIdx.x * 4 + wave;

    const float4* __restrict__ w4 = (const float4*)(W + (size_t)row * H);

    float acc = 0.f;
#pragma unroll
    for (int it = 0; it < H / (64 * 4); ++it) {      // 16 iters
        const int k = it * 64 + lane;                // float4 index
        float4 w = w4[k];
        float4 h = sx4[k];
        acc += w.x * h.x + w.y * h.y + w.z * h.z + w.w * h.w;
    }

    // wave-64 reduction
#pragma unroll
    for (int off = 32; off > 0; off >>= 1)
        acc += __shfl_down(acc, off, 64);

    if (lane == 0) {
        float v = acc + b1[row];
        if (b2) v += b2[row];
        y[row] = do_tanh ? tanhf(v) : v;
    }
}

extern "C" void kernel_launch(void* const* d_in, const int* in_sizes, int n_in,
                              void* d_out, int out_size, void* d_ws, size_t ws_size,
                              hipStream_t stream) {
    const float* x    = (const float*)d_in[0];
    const float* Wxh  = (const float*)d_in[1];  // [8, H, H]
    const float* bxh  = (const float*)d_in[2];  // [8, H]
    // d_in[3] = Whh: multiplied by a zero hidden state -> only its bias matters
    const float* bhh  = (const float*)d_in[4];  // [8, H]
    const float* fc_w = (const float*)d_in[5];  // [H, H]
    const float* fc_b = (const float*)d_in[6];  // [H]
    float* out = (float*)d_out;

    // ping-pong hidden-state buffers in workspace (2 * 16 KiB)
    float* h0 = (float*)d_ws;
    float* h1 = h0 + H;
    float* buf[2] = { h0, h1 };

    const float* cur = x;
    for (int l = 0; l < NLAYERS; ++l) {
        float* dst = buf[l & 1];
        gemv_bias_act<<<H / 4, 256, 0, stream>>>(
            Wxh + (size_t)l * H * H, bxh + (size_t)l * H, bhh + (size_t)l * H,
            cur, dst, 1);
        cur = dst;
    }
    gemv_bias_act<<<H / 4, 256, 0, stream>>>(fc_w, fc_b, nullptr, cur, out, 0);
}